// Round 1
// baseline (267.943 us; speedup 1.0000x reference)
//
#include <hip/hip_runtime.h>
#include <hip/hip_bf16.h>
#include <math.h>

#define PATCH 41
#define PP 1681          // 41*41
#define NB 8
#define KS 16            // pooling kernel size
#define STRIDE 10
#define PAD 4

__device__ __forceinline__ int imax(int a, int b) { return a > b ? a : b; }
__device__ __forceinline__ int imin(int a, int b) { return a < b ? a : b; }

// block-wide sum over 256 threads (4 waves). All threads must call.
__device__ __forceinline__ float block_sum(float v, float* s_red, int t) {
    #pragma unroll
    for (int o = 32; o > 0; o >>= 1) v += __shfl_xor(v, o);
    if ((t & 63) == 0) s_red[t >> 6] = v;
    __syncthreads();
    float total = s_red[0] + s_red[1] + s_red[2] + s_red[3];
    __syncthreads();   // protect s_red for next call
    return total;
}

__global__ __launch_bounds__(256) void sift_desc_kernel(
        const float* __restrict__ x,   // [N,1,41,41]
        const float* __restrict__ gk,  // [41,41]
        const float* __restrict__ pk,  // [16,16]
        float* __restrict__ out)       // [N,128]
{
    const int patch = blockIdx.x;
    const int t = threadIdx.x;

    __shared__ float s_x[PP];
    __shared__ float s_contrib[NB * PP];   // [bin][41*41]
    __shared__ float s_pk[KS * KS];
    __shared__ float s_desc[128];
    __shared__ float s_red[4];

    // ---- stage 0: load patch + pooling kernel into LDS ----
    const float* xp = x + (size_t)patch * PP;
    for (int p = t; p < PP; p += 256) s_x[p] = xp[p];
    s_pk[t] = pk[t];   // t in [0,256)
    __syncthreads();

    // ---- stage 1: gradients, orientation binning -> dense contrib ----
    const float TWO_PI = 6.283185307179586f;
    const float SCALE  = 8.0f / TWO_PI;
    for (int p = t; p < PP; p += 256) {
        int i = p / PATCH;
        int j = p - i * PATCH;
        float xl = s_x[i * PATCH + (j > 0 ? j - 1 : 0)];
        float xr = s_x[i * PATCH + (j < PATCH - 1 ? j + 1 : PATCH - 1)];
        float xu = s_x[(i > 0 ? i - 1 : 0) * PATCH + j];
        float xd = s_x[(i < PATCH - 1 ? i + 1 : PATCH - 1) * PATCH + j];
        float gxv = xr - xl;
        float gyv = xd - xu;
        float mag = sqrtf(gxv * gxv + gyv * gyv + 1e-10f) * gk[p];
        float ori = atan2f(gyv, gxv + 1e-10f);
        float o = (ori + TWO_PI) * SCALE;      // in [4,12]
        float f = floorf(o);
        float w1 = o - f;
        int b0 = ((int)f) & 7;
        int b1 = (b0 + 1) & 7;
        float m0 = (1.0f - w1) * mag;
        float m1 = w1 * mag;
        #pragma unroll
        for (int b = 0; b < NB; ++b) {
            float v = (b == b0) ? m0 : ((b == b1) ? m1 : 0.0f);
            s_contrib[b * PP + p] = v;
        }
    }
    __syncthreads();

    // ---- stage 2: depthwise 16x16 pooling, stride 10, pad 4 ----
    // 128 output cells, 2 threads per cell (ky halves).
    const int pair = t >> 1;          // 0..127 == descriptor index b*16 + oy*4 + ox
    const int half = t & 1;
    const int b    = pair >> 4;
    const int cell = pair & 15;
    const int oy = cell >> 2, ox = cell & 3;
    const int iy0 = oy * STRIDE - PAD;
    const int ix0 = ox * STRIDE - PAD;

    const int ky_lo = imax(half * 8,     imax(0, -iy0));
    const int ky_hi = imin(half * 8 + 7, imin(KS - 1, PATCH - 1 - iy0));
    const int kx_lo = imax(0, -ix0);
    const int kx_hi = imin(KS - 1, PATCH - 1 - ix0);

    float acc = 0.0f;
    for (int ky = ky_lo; ky <= ky_hi; ++ky) {
        const int iy = iy0 + ky;
        const float* crow = &s_contrib[b * PP + iy * PATCH + ix0];
        const float* prow = &s_pk[ky * KS];
        for (int kx = kx_lo; kx <= kx_hi; ++kx) {
            acc = fmaf(crow[kx], prow[kx], acc);
        }
    }
    acc += __shfl_xor(acc, 1);        // combine the two ky-halves
    if (half == 0) s_desc[pair] = acc;
    __syncthreads();

    // ---- stage 3: L2 -> clip 0.2 -> L2 -> L1 -> sqrt ----
    float v = (t < 128) ? s_desc[t] : 0.0f;

    float sumsq = block_sum(v * v, s_red, t);
    v *= 1.0f / fmaxf(sqrtf(sumsq), 1e-12f);
    v = fminf(fmaxf(v, 0.0f), 0.2f);

    float sumsq2 = block_sum(v * v, s_red, t);
    v *= 1.0f / fmaxf(sqrtf(sumsq2), 1e-12f);

    float l1 = block_sum(v, s_red, t);   // v >= 0 after clip
    v = v / fmaxf(l1, 1e-12f);

    if (t < 128) out[(size_t)patch * 128 + t] = sqrtf(v + 1e-10f);
}

extern "C" void kernel_launch(void* const* d_in, const int* in_sizes, int n_in,
                              void* d_out, int out_size, void* d_ws, size_t ws_size,
                              hipStream_t stream) {
    const float* x  = (const float*)d_in[0];
    const float* gk = (const float*)d_in[1];
    const float* pk = (const float*)d_in[2];
    float* out = (float*)d_out;
    const int n = in_sizes[0] / PP;   // 8192 patches
    sift_desc_kernel<<<n, 256, 0, stream>>>(x, gk, pk, out);
}